// Round 5
// baseline (574.700 us; speedup 1.0000x reference)
//
#include <hip/hip_runtime.h>
#include <stdint.h>

// ---------------------------------------------------------------------------
// VQ-VAE layer, all-bf16 MFMA pipeline.
// R4 -> R5: vq_dist was latency-bound at 2 blocks/CU (grid 512, occupancy 23%,
// MfmaUtil 22%, zero conflicts). VGPR=112 permits 4 waves/SIMD, so the cap was
// the GRID. Split codebook 2-ways across blockIdx.x -> grid 1024 = 4 blocks/CU,
// merging per-row winners via u64 atomicMin (lowest-code tie-break preserved).
// B-traffic through L2 unchanged. No new registers (prefetch would tip the
// 4-waves/SIMD boundary).
// ---------------------------------------------------------------------------

typedef short bf16x8 __attribute__((ext_vector_type(8)));
typedef float f32x4 __attribute__((ext_vector_type(4)));

__device__ __forceinline__ void gl2lds16(const void* g, void* l) {
  __builtin_amdgcn_global_load_lds(
      (const __attribute__((address_space(1))) void*)g,
      (__attribute__((address_space(3))) void*)l, 16, 0, 0);
}

__device__ __forceinline__ float bf2f(unsigned short u) {
  return __uint_as_float(((unsigned)u) << 16);
}
__device__ __forceinline__ unsigned short f2bf(float f) {
  unsigned x = __float_as_uint(f);
  unsigned r = (x + 0x7fffu + ((x >> 16) & 1u)) >> 16;  // RNE
  return (unsigned short)r;
}
__device__ __forceinline__ unsigned long long packScore(float s, int code) {
  unsigned u = __float_as_uint(s);
  u = (u & 0x80000000u) ? ~u : (u | 0x80000000u);  // monotone map f32 -> u32
  return ((unsigned long long)u << 32) | (unsigned)code;
}
__device__ __forceinline__ unsigned long long shflxor_u64(unsigned long long v, int m) {
  union { unsigned long long u; int i[2]; } a;
  a.u = v;
  a.i[0] = __shfl_xor(a.i[0], m);
  a.i[1] = __shfl_xor(a.i[1], m);
  return a.u;
}

// ---------------------------------------------------------------------------
// cast fp32 -> bf16 (vectorized, n4 = count/4)
__global__ __launch_bounds__(256)
void cast_bf16(const float* __restrict__ X, unsigned short* __restrict__ Y, int n4) {
  int i = blockIdx.x * 256 + threadIdx.x;
  if (i < n4) {
    float4 v = ((const float4*)X)[i];
    ushort4 o = make_ushort4(f2bf(v.x), f2bf(v.y), f2bf(v.z), f2bf(v.w));
    ((ushort4*)Y)[i] = o;
  }
}

// transpose 1024x1024 fp32 W[i][j] -> bf16 Wt[j][i]
__global__ __launch_bounds__(256)
void transpose_cast(const float* __restrict__ W, unsigned short* __restrict__ Wt, int D) {
  __shared__ float s[32][33];
  int tx = threadIdx.x & 31, ty = threadIdx.x >> 5;  // 32x8
  int bx = blockIdx.x, by = blockIdx.y;
#pragma unroll
  for (int p = 0; p < 4; p++) {
    int r = by * 32 + ty + p * 8, c = bx * 32 + tx;
    s[ty + p * 8][tx] = W[(size_t)r * D + c];
  }
  __syncthreads();
#pragma unroll
  for (int p = 0; p < 4; p++) {
    int r = bx * 32 + ty + p * 8, c = by * 32 + tx;
    Wt[(size_t)r * D + c] = f2bf(s[tx][ty + p * 8]);
  }
}

// per-code squared norms (fp32), one wave per code row of 256
__global__ __launch_bounds__(256)
void code_norms(const float* __restrict__ cb, float* __restrict__ cn) {
  int row = blockIdx.x * 4 + (threadIdx.x >> 6);
  int lane = threadIdx.x & 63;
  float4 v = ((const float4*)(cb + (size_t)row * 256))[lane];
  float s = v.x * v.x + v.y * v.y + v.z * v.z + v.w * v.w;
#pragma unroll
  for (int off = 32; off > 0; off >>= 1) s += __shfl_down(s, off);
  if (lane == 0) cn[row] = s;
}

// ---------------------------------------------------------------------------
// GEMM: C[M,N] fp32 = relu(A[M,K]bf16 @ Bt[N,K]^T bf16 + bias)
// 128x128 tile, BK=64, DMA staging (global_load_lds w=16) + XOR swizzle.
__global__ __launch_bounds__(256, 2)
void gemm_bias_relu(const unsigned short* __restrict__ A, const unsigned short* __restrict__ Bt,
                    const float* __restrict__ bias, float* __restrict__ C,
                    int M, int N, int K) {
  __shared__ unsigned short As[128 * 64];
  __shared__ unsigned short Bs[128 * 64];
  const int t = threadIdx.x;
  const int wv = t >> 6, lane = t & 63;
  const int wm = wv >> 1, wn = wv & 1;
  const int quad = lane >> 4, l15 = lane & 15;
  const int row0 = blockIdx.y * 128, col0 = blockIdx.x * 128;
  const int rsub = lane >> 3;            // row within 8-row slab
  const int dchunk = (lane & 7) ^ rsub;  // xor-swizzled data chunk to fetch

  f32x4 acc[4][4];
#pragma unroll
  for (int i = 0; i < 4; i++)
#pragma unroll
    for (int j = 0; j < 4; j++) acc[i][j] = (f32x4){0.f, 0.f, 0.f, 0.f};

  for (int k0 = 0; k0 < K; k0 += 64) {
#pragma unroll
    for (int j = 0; j < 4; j++) {
      int slab = j * 4 + wv;            // 16 slabs of 8 rows (1024 B each)
      int row = slab * 8 + rsub;
      gl2lds16(A + (size_t)(row0 + row) * K + k0 + dchunk * 8, As + slab * 512);
      gl2lds16(Bt + (size_t)(col0 + row) * K + k0 + dchunk * 8, Bs + slab * 512);
    }
    __syncthreads();
#pragma unroll
    for (int kk = 0; kk < 2; kk++) {
      bf16x8 af[4], bfr[4];
#pragma unroll
      for (int mt = 0; mt < 4; mt++) {
        int row = wm * 64 + mt * 16 + l15;
        af[mt] = *(const bf16x8*)(As + row * 64 + (((kk * 4 + quad) ^ (l15 & 7)) * 8));
      }
#pragma unroll
      for (int nt = 0; nt < 4; nt++) {
        int row = wn * 64 + nt * 16 + l15;
        bfr[nt] = *(const bf16x8*)(Bs + row * 64 + (((kk * 4 + quad) ^ (l15 & 7)) * 8));
      }
#pragma unroll
      for (int mt = 0; mt < 4; mt++)
#pragma unroll
        for (int nt = 0; nt < 4; nt++)
          acc[mt][nt] = __builtin_amdgcn_mfma_f32_16x16x32_bf16(af[mt], bfr[nt], acc[mt][nt], 0, 0, 0);
    }
    __syncthreads();
  }
#pragma unroll
  for (int mt = 0; mt < 4; mt++) {
#pragma unroll
    for (int nt = 0; nt < 4; nt++) {
      int col = col0 + wn * 64 + nt * 16 + l15;
      float b = bias[col];
#pragma unroll
      for (int r = 0; r < 4; r++) {
        int row = row0 + wm * 64 + mt * 16 + quad * 4 + r;
        float v = acc[mt][nt][r] + b;
        C[(size_t)row * N + col] = v > 0.f ? v : 0.f;
      }
    }
  }
}

// ---------------------------------------------------------------------------
// LayerNorm over rows of 1024; writes bf16 (obf) or fp32 (of32)
__global__ __launch_bounds__(256)
void ln_kernel(const float* __restrict__ X, const float* __restrict__ g,
               const float* __restrict__ b, unsigned short* __restrict__ obf,
               float* __restrict__ of32) {
  const int row = blockIdx.x, t = threadIdx.x;
  float4 v = ((const float4*)(X + (size_t)row * 1024))[t];
  float s = v.x + v.y + v.z + v.w;
  float ss = v.x * v.x + v.y * v.y + v.z * v.z + v.w * v.w;
#pragma unroll
  for (int off = 32; off > 0; off >>= 1) {
    s += __shfl_down(s, off);
    ss += __shfl_down(ss, off);
  }
  __shared__ float rs[4], rss[4];
  const int wave = t >> 6, lane = t & 63;
  if (lane == 0) { rs[wave] = s; rss[wave] = ss; }
  __syncthreads();
  float S = rs[0] + rs[1] + rs[2] + rs[3];
  float SS = rss[0] + rss[1] + rss[2] + rss[3];
  float m = S * (1.0f / 1024.0f);
  float var = SS * (1.0f / 1024.0f) - m * m;
  float rstd = 1.0f / sqrtf(var + 1e-5f);
  float4 gv = ((const float4*)g)[t];
  float4 bv = ((const float4*)b)[t];
  float4 o;
  o.x = (v.x - m) * rstd * gv.x + bv.x;
  o.y = (v.y - m) * rstd * gv.y + bv.y;
  o.z = (v.z - m) * rstd * gv.z + bv.z;
  o.w = (v.w - m) * rstd * gv.w + bv.w;
  if (obf) {
    ushort4 u = make_ushort4(f2bf(o.x), f2bf(o.y), f2bf(o.z), f2bf(o.w));
    ((ushort4*)(obf + (size_t)row * 1024))[t] = u;
  } else {
    ((float4*)(of32 + (size_t)row * 1024))[t] = o;
  }
}

// ---------------------------------------------------------------------------
// VQ distance+argmin: Z[32768,256]bf16 vs Cb[8192,256]bf16.
// Block = 64 Z-rows x 4096-code half (blockIdx.x selects half). Z register-
// resident (zf[4][8]); B streamed global->VGPR (codebook L2-resident). No
// LDS/barriers in main loop. Wave wv owns codes [half + ch*128 + wv*32, +32).
__global__ __launch_bounds__(256, 2)
void vq_dist(const unsigned short* __restrict__ Z, const unsigned short* __restrict__ Cb,
             const float* __restrict__ cnorm, unsigned long long* __restrict__ bestg) {
  __shared__ unsigned long long runmin[64];
  const int t = threadIdx.x;
  const int wv = t >> 6, lane = t & 63;
  const int quad = lane >> 4, l15 = lane & 15;
  const int row0 = blockIdx.y * 64;
  const int cstart = blockIdx.x * 4096;

  if (t < 64) runmin[t] = ~0ull;

  // Z fragments for this wave: rows mt*16+l15, K-step ks (8 bf16 each)
  bf16x8 zf[4][8];
#pragma unroll
  for (int mt = 0; mt < 4; mt++)
#pragma unroll
    for (int ks = 0; ks < 8; ks++)
      zf[mt][ks] = *(const bf16x8*)(Z + (size_t)(row0 + mt * 16 + l15) * 256 + ks * 32 + quad * 8);

  float msc[4][4];
  int mcd[4][4];
#pragma unroll
  for (int mt = 0; mt < 4; mt++)
#pragma unroll
    for (int r = 0; r < 4; r++) { msc[mt][r] = 3.4e38f; mcd[mt][r] = 0; }

  for (int ch = 0; ch < 32; ch++) {
    const int code0 = cstart + ch * 128 + wv * 32 + l15;  // + nt*16
    const unsigned short* cptr = Cb + (size_t)code0 * 256 + quad * 8;
    f32x4 acc[4][2];
#pragma unroll
    for (int mt = 0; mt < 4; mt++)
#pragma unroll
      for (int nt = 0; nt < 2; nt++) acc[mt][nt] = (f32x4){0.f, 0.f, 0.f, 0.f};

#pragma unroll
    for (int ks = 0; ks < 8; ks++) {
      bf16x8 bfr[2];
#pragma unroll
      for (int nt = 0; nt < 2; nt++)
        bfr[nt] = *(const bf16x8*)(cptr + (size_t)nt * 16 * 256 + ks * 32);
#pragma unroll
      for (int mt = 0; mt < 4; mt++)
#pragma unroll
        for (int nt = 0; nt < 2; nt++)
          acc[mt][nt] = __builtin_amdgcn_mfma_f32_16x16x32_bf16(zf[mt][ks], bfr[nt], acc[mt][nt], 0, 0, 0);
    }
    // cheap float argmin update; codes visited in ascending order per lane,
    // strict < keeps the lowest index (reference tie-break)
#pragma unroll
    for (int nt = 0; nt < 2; nt++) {
      int code = code0 + nt * 16;
      float cn = cnorm[code];
#pragma unroll
      for (int mt = 0; mt < 4; mt++)
#pragma unroll
        for (int r = 0; r < 4; r++) {
          float sc = cn - 2.0f * acc[mt][nt][r];
          if (sc < msc[mt][r]) { msc[mt][r] = sc; mcd[mt][r] = code; }
        }
    }
  }

  __syncthreads();  // runmin init visible before atomics
#pragma unroll
  for (int mt = 0; mt < 4; mt++) {
#pragma unroll
    for (int r = 0; r < 4; r++) {
      unsigned long long bp = packScore(msc[mt][r], mcd[mt][r]);
#pragma unroll
      for (int m = 1; m < 16; m <<= 1) {
        unsigned long long o = shflxor_u64(bp, m);
        bp = o < bp ? o : bp;
      }
      if (l15 == 0) atomicMin(&runmin[mt * 16 + quad * 4 + r], bp);
    }
  }
  __syncthreads();
  if (t < 64) atomicMin(&bestg[row0 + t], runmin[t]);  // merge the 2 code-halves
}

// ---------------------------------------------------------------------------
// gather quantized rows (bf16 for decoder), histogram, per-block loss partial
__global__ __launch_bounds__(256)
void vq_gather(const unsigned long long* __restrict__ bestg, const float* __restrict__ cb,
               const unsigned short* __restrict__ zb, unsigned short* __restrict__ qb,
               int* __restrict__ counts, float* __restrict__ lpart) {
  const int wave = threadIdx.x >> 6;
  const int g = blockIdx.x * 4 + wave;
  const int lane = threadIdx.x & 63;
  const int idx = (int)(bestg[g] & 0xFFFFFFFFull);
  float4 c = ((const float4*)(cb + (size_t)idx * 256))[lane];
  ushort4 q = make_ushort4(f2bf(c.x), f2bf(c.y), f2bf(c.z), f2bf(c.w));
  ((ushort4*)(qb + (size_t)g * 256))[lane] = q;
  ushort4 z = ((const ushort4*)(zb + (size_t)g * 256))[lane];
  float dx = c.x - bf2f(z.x), dy = c.y - bf2f(z.y);
  float dz = c.z - bf2f(z.z), dw = c.w - bf2f(z.w);
  float p = dx * dx + dy * dy + dz * dz + dw * dw;
#pragma unroll
  for (int off = 32; off > 0; off >>= 1) p += __shfl_down(p, off);
  __shared__ float sp[4];
  if (lane == 0) {
    sp[wave] = p;
    atomicAdd(&counts[idx], 1);
  }
  __syncthreads();
  if (threadIdx.x == 0) lpart[blockIdx.x] = sp[0] + sp[1] + sp[2] + sp[3];
}

// loss + perplexity scalars
__global__ __launch_bounds__(256)
void finalize(const int* __restrict__ counts, const float* __restrict__ lpart,
              float* __restrict__ out2) {
  const int t = threadIdx.x;
  double h = 0.0, l = 0.0;
  for (int i = t; i < 8192; i += 256) {
    double pr = (double)counts[i] * (1.0 / 32768.0);
    h += pr * log(pr + 1e-10);
    l += (double)lpart[i];
  }
  __shared__ double sh[256], sl[256];
  sh[t] = h;
  sl[t] = l;
  __syncthreads();
  for (int w = 128; w > 0; w >>= 1) {
    if (t < w) { sh[t] += sh[t + w]; sl[t] += sl[t + w]; }
    __syncthreads();
  }
  if (t == 0) {
    out2[0] = (float)(1.25 * sl[0] * (1.0 / 8388608.0));
    out2[1] = (float)exp(-sh[0]);
  }
}

// ---------------------------------------------------------------------------
extern "C" void kernel_launch(void* const* d_in, const int* in_sizes, int n_in,
                              void* d_out, int out_size, void* d_ws, size_t ws_size,
                              hipStream_t stream) {
  const float* x = (const float*)d_in[0];
  const float* We1 = (const float*)d_in[1];
  const float* be1 = (const float*)d_in[2];
  const float* ge1 = (const float*)d_in[3];
  const float* bne1 = (const float*)d_in[4];
  const float* We2 = (const float*)d_in[5];
  const float* be2 = (const float*)d_in[6];
  const float* ge2 = (const float*)d_in[7];
  const float* bne2 = (const float*)d_in[8];
  const float* Wd1 = (const float*)d_in[9];
  const float* bd1 = (const float*)d_in[10];
  const float* gd1 = (const float*)d_in[11];
  const float* bnd1 = (const float*)d_in[12];
  const float* Wd2 = (const float*)d_in[13];
  const float* bd2 = (const float*)d_in[14];
  const float* gd2 = (const float*)d_in[15];
  const float* bnd2 = (const float*)d_in[16];
  const float* codebook = (const float*)d_in[17];
  float* out = (float*)d_out;

  char* w = (char*)d_ws;
  auto alloc = [&](size_t bytes) -> char* {
    char* p = w;
    w += (bytes + 255) & ~(size_t)255;
    return p;
  };
  unsigned short* xb = (unsigned short*)alloc((size_t)8192 * 1024 * 2);
  unsigned short* wt0 = (unsigned short*)alloc((size_t)1024 * 1024 * 2);
  unsigned short* wt1 = (unsigned short*)alloc((size_t)1024 * 1024 * 2);
  unsigned short* wt2 = (unsigned short*)alloc((size_t)1024 * 1024 * 2);
  unsigned short* wt3 = (unsigned short*)alloc((size_t)1024 * 1024 * 2);
  unsigned short* cbb = (unsigned short*)alloc((size_t)8192 * 256 * 2);
  float* cnorm = (float*)alloc((size_t)8192 * 4);
  float* act = (float*)alloc((size_t)8192 * 1024 * 4);
  unsigned short* yb = (unsigned short*)alloc((size_t)8192 * 1024 * 2);
  unsigned short* zb = (unsigned short*)alloc((size_t)8192 * 1024 * 2);
  unsigned short* qb = (unsigned short*)alloc((size_t)8192 * 1024 * 2);
  unsigned long long* best = (unsigned long long*)alloc((size_t)32768 * 8);
  int* counts = (int*)alloc((size_t)8192 * 4);
  float* lpart = (float*)alloc((size_t)8192 * 4);

  hipMemsetAsync(best, 0xFF, (size_t)32768 * 8, stream);
  hipMemsetAsync(counts, 0, (size_t)8192 * 4, stream);

  cast_bf16<<<(2097152 + 255) / 256, 256, 0, stream>>>(x, xb, 2097152);
  dim3 tg(32, 32);
  transpose_cast<<<tg, 256, 0, stream>>>(We1, wt0, 1024);
  transpose_cast<<<tg, 256, 0, stream>>>(We2, wt1, 1024);
  transpose_cast<<<tg, 256, 0, stream>>>(Wd1, wt2, 1024);
  transpose_cast<<<tg, 256, 0, stream>>>(Wd2, wt3, 1024);
  cast_bf16<<<(524288 + 255) / 256, 256, 0, stream>>>(codebook, cbb, 524288);
  code_norms<<<2048, 256, 0, stream>>>(codebook, cnorm);

  dim3 gg(8, 64);
  // encoder
  gemm_bias_relu<<<gg, 256, 0, stream>>>(xb, wt0, be1, act, 8192, 1024, 1024);
  ln_kernel<<<8192, 256, 0, stream>>>(act, ge1, bne1, yb, nullptr);
  gemm_bias_relu<<<gg, 256, 0, stream>>>(yb, wt1, be2, act, 8192, 1024, 1024);
  ln_kernel<<<8192, 256, 0, stream>>>(act, ge2, bne2, zb, nullptr);
  // VQ
  dim3 vqg(2, 512);
  vq_dist<<<vqg, 256, 0, stream>>>(zb, cbb, cnorm, best);
  vq_gather<<<8192, 256, 0, stream>>>(best, codebook, zb, qb, counts, lpart);
  // decoder
  gemm_bias_relu<<<gg, 256, 0, stream>>>(qb, wt2, bd1, act, 8192, 1024, 1024);
  ln_kernel<<<8192, 256, 0, stream>>>(act, gd1, bnd1, yb, nullptr);
  gemm_bias_relu<<<gg, 256, 0, stream>>>(yb, wt3, bd2, act, 8192, 1024, 1024);
  ln_kernel<<<8192, 256, 0, stream>>>(act, gd2, bnd2, nullptr, out);

  finalize<<<1, 256, 0, stream>>>(counts, lpart, out + 8388608);
}

// Round 6
// 552.356 us; speedup vs baseline: 1.0405x; 1.0405x over previous
//
#include <hip/hip_runtime.h>
#include <stdint.h>

// ---------------------------------------------------------------------------
// VQ-VAE layer, all-bf16 MFMA pipeline.
// R5 -> R6: occupancy is register-capped (unified VGPR+AGPR ~176/wave -> 2
// blocks/CU no matter the grid; R5's grid-doubling proved it). vq_dist's real
// stall: per-ks "load pair -> waitcnt -> 8 MFMA" serialization (~200-400 cyc
// exposed L2 latency per step, MfmaUtil 20%). Fix: 2-deep ping-pong prefetch
// of B fragments (bbuf[2][2]) so step ks+1's loads are in flight during step
// ks's MFMAs; zero-C first MFMA per chunk (no acc zero-init); cnorm
// prefetched at chunk top. Topology back to R4: grid 512, full codebook per
// block, plain bestg store (no memset, no global atomic).
// ---------------------------------------------------------------------------

typedef short bf16x8 __attribute__((ext_vector_type(8)));
typedef float f32x4 __attribute__((ext_vector_type(4)));

__device__ __forceinline__ void gl2lds16(const void* g, void* l) {
  __builtin_amdgcn_global_load_lds(
      (const __attribute__((address_space(1))) void*)g,
      (__attribute__((address_space(3))) void*)l, 16, 0, 0);
}

__device__ __forceinline__ float bf2f(unsigned short u) {
  return __uint_as_float(((unsigned)u) << 16);
}
__device__ __forceinline__ unsigned short f2bf(float f) {
  unsigned x = __float_as_uint(f);
  unsigned r = (x + 0x7fffu + ((x >> 16) & 1u)) >> 16;  // RNE
  return (unsigned short)r;
}
__device__ __forceinline__ unsigned long long packScore(float s, int code) {
  unsigned u = __float_as_uint(s);
  u = (u & 0x80000000u) ? ~u : (u | 0x80000000u);  // monotone map f32 -> u32
  return ((unsigned long long)u << 32) | (unsigned)code;
}
__device__ __forceinline__ unsigned long long shflxor_u64(unsigned long long v, int m) {
  union { unsigned long long u; int i[2]; } a;
  a.u = v;
  a.i[0] = __shfl_xor(a.i[0], m);
  a.i[1] = __shfl_xor(a.i[1], m);
  return a.u;
}

// ---------------------------------------------------------------------------
// cast fp32 -> bf16 (vectorized, n4 = count/4)
__global__ __launch_bounds__(256)
void cast_bf16(const float* __restrict__ X, unsigned short* __restrict__ Y, int n4) {
  int i = blockIdx.x * 256 + threadIdx.x;
  if (i < n4) {
    float4 v = ((const float4*)X)[i];
    ushort4 o = make_ushort4(f2bf(v.x), f2bf(v.y), f2bf(v.z), f2bf(v.w));
    ((ushort4*)Y)[i] = o;
  }
}

// transpose 1024x1024 fp32 W[i][j] -> bf16 Wt[j][i]
__global__ __launch_bounds__(256)
void transpose_cast(const float* __restrict__ W, unsigned short* __restrict__ Wt, int D) {
  __shared__ float s[32][33];
  int tx = threadIdx.x & 31, ty = threadIdx.x >> 5;  // 32x8
  int bx = blockIdx.x, by = blockIdx.y;
#pragma unroll
  for (int p = 0; p < 4; p++) {
    int r = by * 32 + ty + p * 8, c = bx * 32 + tx;
    s[ty + p * 8][tx] = W[(size_t)r * D + c];
  }
  __syncthreads();
#pragma unroll
  for (int p = 0; p < 4; p++) {
    int r = bx * 32 + ty + p * 8, c = by * 32 + tx;
    Wt[(size_t)r * D + c] = f2bf(s[tx][ty + p * 8]);
  }
}

// per-code squared norms (fp32), one wave per code row of 256
__global__ __launch_bounds__(256)
void code_norms(const float* __restrict__ cb, float* __restrict__ cn) {
  int row = blockIdx.x * 4 + (threadIdx.x >> 6);
  int lane = threadIdx.x & 63;
  float4 v = ((const float4*)(cb + (size_t)row * 256))[lane];
  float s = v.x * v.x + v.y * v.y + v.z * v.z + v.w * v.w;
#pragma unroll
  for (int off = 32; off > 0; off >>= 1) s += __shfl_down(s, off);
  if (lane == 0) cn[row] = s;
}

// ---------------------------------------------------------------------------
// GEMM: C[M,N] fp32 = relu(A[M,K]bf16 @ Bt[N,K]^T bf16 + bias)
// 128x128 tile, BK=64, DMA staging (global_load_lds w=16) + XOR swizzle.
__global__ __launch_bounds__(256, 2)
void gemm_bias_relu(const unsigned short* __restrict__ A, const unsigned short* __restrict__ Bt,
                    const float* __restrict__ bias, float* __restrict__ C,
                    int M, int N, int K) {
  __shared__ unsigned short As[128 * 64];
  __shared__ unsigned short Bs[128 * 64];
  const int t = threadIdx.x;
  const int wv = t >> 6, lane = t & 63;
  const int wm = wv >> 1, wn = wv & 1;
  const int quad = lane >> 4, l15 = lane & 15;
  const int row0 = blockIdx.y * 128, col0 = blockIdx.x * 128;
  const int rsub = lane >> 3;            // row within 8-row slab
  const int dchunk = (lane & 7) ^ rsub;  // xor-swizzled data chunk to fetch

  f32x4 acc[4][4];
#pragma unroll
  for (int i = 0; i < 4; i++)
#pragma unroll
    for (int j = 0; j < 4; j++) acc[i][j] = (f32x4){0.f, 0.f, 0.f, 0.f};

  for (int k0 = 0; k0 < K; k0 += 64) {
#pragma unroll
    for (int j = 0; j < 4; j++) {
      int slab = j * 4 + wv;            // 16 slabs of 8 rows (1024 B each)
      int row = slab * 8 + rsub;
      gl2lds16(A + (size_t)(row0 + row) * K + k0 + dchunk * 8, As + slab * 512);
      gl2lds16(Bt + (size_t)(col0 + row) * K + k0 + dchunk * 8, Bs + slab * 512);
    }
    __syncthreads();
#pragma unroll
    for (int kk = 0; kk < 2; kk++) {
      bf16x8 af[4], bfr[4];
#pragma unroll
      for (int mt = 0; mt < 4; mt++) {
        int row = wm * 64 + mt * 16 + l15;
        af[mt] = *(const bf16x8*)(As + row * 64 + (((kk * 4 + quad) ^ (l15 & 7)) * 8));
      }
#pragma unroll
      for (int nt = 0; nt < 4; nt++) {
        int row = wn * 64 + nt * 16 + l15;
        bfr[nt] = *(const bf16x8*)(Bs + row * 64 + (((kk * 4 + quad) ^ (l15 & 7)) * 8));
      }
#pragma unroll
      for (int mt = 0; mt < 4; mt++)
#pragma unroll
        for (int nt = 0; nt < 4; nt++)
          acc[mt][nt] = __builtin_amdgcn_mfma_f32_16x16x32_bf16(af[mt], bfr[nt], acc[mt][nt], 0, 0, 0);
    }
    __syncthreads();
  }
#pragma unroll
  for (int mt = 0; mt < 4; mt++) {
#pragma unroll
    for (int nt = 0; nt < 4; nt++) {
      int col = col0 + wn * 64 + nt * 16 + l15;
      float b = bias[col];
#pragma unroll
      for (int r = 0; r < 4; r++) {
        int row = row0 + wm * 64 + mt * 16 + quad * 4 + r;
        float v = acc[mt][nt][r] + b;
        C[(size_t)row * N + col] = v > 0.f ? v : 0.f;
      }
    }
  }
}

// ---------------------------------------------------------------------------
// LayerNorm over rows of 1024; writes bf16 (obf) or fp32 (of32)
__global__ __launch_bounds__(256)
void ln_kernel(const float* __restrict__ X, const float* __restrict__ g,
               const float* __restrict__ b, unsigned short* __restrict__ obf,
               float* __restrict__ of32) {
  const int row = blockIdx.x, t = threadIdx.x;
  float4 v = ((const float4*)(X + (size_t)row * 1024))[t];
  float s = v.x + v.y + v.z + v.w;
  float ss = v.x * v.x + v.y * v.y + v.z * v.z + v.w * v.w;
#pragma unroll
  for (int off = 32; off > 0; off >>= 1) {
    s += __shfl_down(s, off);
    ss += __shfl_down(ss, off);
  }
  __shared__ float rs[4], rss[4];
  const int wave = t >> 6, lane = t & 63;
  if (lane == 0) { rs[wave] = s; rss[wave] = ss; }
  __syncthreads();
  float S = rs[0] + rs[1] + rs[2] + rs[3];
  float SS = rss[0] + rss[1] + rss[2] + rss[3];
  float m = S * (1.0f / 1024.0f);
  float var = SS * (1.0f / 1024.0f) - m * m;
  float rstd = 1.0f / sqrtf(var + 1e-5f);
  float4 gv = ((const float4*)g)[t];
  float4 bv = ((const float4*)b)[t];
  float4 o;
  o.x = (v.x - m) * rstd * gv.x + bv.x;
  o.y = (v.y - m) * rstd * gv.y + bv.y;
  o.z = (v.z - m) * rstd * gv.z + bv.z;
  o.w = (v.w - m) * rstd * gv.w + bv.w;
  if (obf) {
    ushort4 u = make_ushort4(f2bf(o.x), f2bf(o.y), f2bf(o.z), f2bf(o.w));
    ((ushort4*)(obf + (size_t)row * 1024))[t] = u;
  } else {
    ((float4*)(of32 + (size_t)row * 1024))[t] = o;
  }
}

// ---------------------------------------------------------------------------
// VQ distance+argmin: Z[32768,256]bf16 vs Cb[8192,256]bf16.
// Block = 64 Z-rows x ALL 8192 codes (grid 512). Z register-resident
// (zf[4][8]); B fragments software-pipelined global->VGPR with 2-deep
// ping-pong (bbuf) so next step's loads are in flight during current MFMAs.
// Wave wv owns codes [ch*128 + wv*32, +32). score = |c|^2 - 2 z.c
__global__ __launch_bounds__(256, 2)
void vq_dist(const unsigned short* __restrict__ Z, const unsigned short* __restrict__ Cb,
             const float* __restrict__ cnorm, unsigned long long* __restrict__ bestg) {
  __shared__ unsigned long long runmin[64];
  const int t = threadIdx.x;
  const int wv = t >> 6, lane = t & 63;
  const int quad = lane >> 4, l15 = lane & 15;
  const int row0 = blockIdx.x * 64;

  if (t < 64) runmin[t] = ~0ull;

  // Z fragments for this wave: rows mt*16+l15, K-step ks (8 bf16 each)
  bf16x8 zf[4][8];
#pragma unroll
  for (int mt = 0; mt < 4; mt++)
#pragma unroll
    for (int ks = 0; ks < 8; ks++)
      zf[mt][ks] = *(const bf16x8*)(Z + (size_t)(row0 + mt * 16 + l15) * 256 + ks * 32 + quad * 8);

  float msc[4][4];
  int mcd[4][4];
#pragma unroll
  for (int mt = 0; mt < 4; mt++)
#pragma unroll
    for (int r = 0; r < 4; r++) { msc[mt][r] = 3.4e38f; mcd[mt][r] = 0; }

  // base pointer for this lane's code column (nt adds 16*256, ch adds 128*256)
  const unsigned short* cbase = Cb + (size_t)(wv * 32 + l15) * 256 + quad * 8;

  bf16x8 bbuf[2][2];
  // preload (ch=0, ks=0)
  bbuf[0][0] = *(const bf16x8*)(cbase);
  bbuf[0][1] = *(const bf16x8*)(cbase + 16 * 256);

  for (int ch = 0; ch < 64; ch++) {
    const size_t choff = (size_t)ch * 32768;  // 128 codes * 256 dims
    // cnorm prefetch for this chunk (done long before the epilogue needs it)
    float cn0 = cnorm[ch * 128 + wv * 32 + l15];
    float cn1 = cnorm[ch * 128 + wv * 32 + l15 + 16];

    f32x4 acc[4][2];
    // ---- ks = 0: prefetch ks=1, MFMA with zero C (no acc init needed) ----
    {
      const unsigned short* np = cbase + choff + 32;  // (ch, ks=1)
      bbuf[1][0] = *(const bf16x8*)(np);
      bbuf[1][1] = *(const bf16x8*)(np + 16 * 256);
      const f32x4 z4 = (f32x4){0.f, 0.f, 0.f, 0.f};
#pragma unroll
      for (int mt = 0; mt < 4; mt++) {
        acc[mt][0] = __builtin_amdgcn_mfma_f32_16x16x32_bf16(zf[mt][0], bbuf[0][0], z4, 0, 0, 0);
        acc[mt][1] = __builtin_amdgcn_mfma_f32_16x16x32_bf16(zf[mt][0], bbuf[0][1], z4, 0, 0, 0);
      }
    }
    // ---- ks = 1..7: prefetch ks+1 (or next chunk's ks=0), MFMA current ----
#pragma unroll
    for (int ks = 1; ks < 8; ks++) {
      const int cur = ks & 1, nxt = cur ^ 1;
      const size_t noff = (ks == 7) ? (size_t)(ch + 1 < 64 ? ch + 1 : 0) * 32768
                                    : choff + (size_t)(ks + 1) * 32;
      const unsigned short* np = cbase + noff;
      bbuf[nxt][0] = *(const bf16x8*)(np);
      bbuf[nxt][1] = *(const bf16x8*)(np + 16 * 256);
#pragma unroll
      for (int mt = 0; mt < 4; mt++) {
        acc[mt][0] = __builtin_amdgcn_mfma_f32_16x16x32_bf16(zf[mt][ks], bbuf[cur][0], acc[mt][0], 0, 0, 0);
        acc[mt][1] = __builtin_amdgcn_mfma_f32_16x16x32_bf16(zf[mt][ks], bbuf[cur][1], acc[mt][1], 0, 0, 0);
      }
    }
    // cheap float argmin update; codes visited in ascending order per lane,
    // strict < keeps the lowest index (reference tie-break)
#pragma unroll
    for (int nt = 0; nt < 2; nt++) {
      int code = ch * 128 + wv * 32 + nt * 16 + l15;
      float cn = nt == 0 ? cn0 : cn1;
#pragma unroll
      for (int mt = 0; mt < 4; mt++)
#pragma unroll
        for (int r = 0; r < 4; r++) {
          float sc = cn - 2.0f * acc[mt][nt][r];
          if (sc < msc[mt][r]) { msc[mt][r] = sc; mcd[mt][r] = code; }
        }
    }
  }

  __syncthreads();  // runmin init visible before atomics
#pragma unroll
  for (int mt = 0; mt < 4; mt++) {
#pragma unroll
    for (int r = 0; r < 4; r++) {
      unsigned long long bp = packScore(msc[mt][r], mcd[mt][r]);
#pragma unroll
      for (int m = 1; m < 16; m <<= 1) {
        unsigned long long o = shflxor_u64(bp, m);
        bp = o < bp ? o : bp;
      }
      if (l15 == 0) atomicMin(&runmin[mt * 16 + quad * 4 + r], bp);
    }
  }
  __syncthreads();
  if (t < 64) bestg[row0 + t] = runmin[t];  // block owns these rows exclusively
}

// ---------------------------------------------------------------------------
// gather quantized rows (bf16 for decoder), histogram, per-block loss partial
__global__ __launch_bounds__(256)
void vq_gather(const unsigned long long* __restrict__ bestg, const float* __restrict__ cb,
               const unsigned short* __restrict__ zb, unsigned short* __restrict__ qb,
               int* __restrict__ counts, float* __restrict__ lpart) {
  const int wave = threadIdx.x >> 6;
  const int g = blockIdx.x * 4 + wave;
  const int lane = threadIdx.x & 63;
  const int idx = (int)(bestg[g] & 0xFFFFFFFFull);
  float4 c = ((const float4*)(cb + (size_t)idx * 256))[lane];
  ushort4 q = make_ushort4(f2bf(c.x), f2bf(c.y), f2bf(c.z), f2bf(c.w));
  ((ushort4*)(qb + (size_t)g * 256))[lane] = q;
  ushort4 z = ((const ushort4*)(zb + (size_t)g * 256))[lane];
  float dx = c.x - bf2f(z.x), dy = c.y - bf2f(z.y);
  float dz = c.z - bf2f(z.z), dw = c.w - bf2f(z.w);
  float p = dx * dx + dy * dy + dz * dz + dw * dw;
#pragma unroll
  for (int off = 32; off > 0; off >>= 1) p += __shfl_down(p, off);
  __shared__ float sp[4];
  if (lane == 0) {
    sp[wave] = p;
    atomicAdd(&counts[idx], 1);
  }
  __syncthreads();
  if (threadIdx.x == 0) lpart[blockIdx.x] = sp[0] + sp[1] + sp[2] + sp[3];
}

// loss + perplexity scalars
__global__ __launch_bounds__(256)
void finalize(const int* __restrict__ counts, const float* __restrict__ lpart,
              float* __restrict__ out2) {
  const int t = threadIdx.x;
  double h = 0.0, l = 0.0;
  for (int i = t; i < 8192; i += 256) {
    double pr = (double)counts[i] * (1.0 / 32768.0);
    h += pr * log(pr + 1e-10);
    l += (double)lpart[i];
  }
  __shared__ double sh[256], sl[256];
  sh[t] = h;
  sl[t] = l;
  __syncthreads();
  for (int w = 128; w > 0; w >>= 1) {
    if (t < w) { sh[t] += sh[t + w]; sl[t] += sl[t + w]; }
    __syncthreads();
  }
  if (t == 0) {
    out2[0] = (float)(1.25 * sl[0] * (1.0 / 8388608.0));
    out2[1] = (float)exp(-sh[0]);
  }
}

// ---------------------------------------------------------------------------
extern "C" void kernel_launch(void* const* d_in, const int* in_sizes, int n_in,
                              void* d_out, int out_size, void* d_ws, size_t ws_size,
                              hipStream_t stream) {
  const float* x = (const float*)d_in[0];
  const float* We1 = (const float*)d_in[1];
  const float* be1 = (const float*)d_in[2];
  const float* ge1 = (const float*)d_in[3];
  const float* bne1 = (const float*)d_in[4];
  const float* We2 = (const float*)d_in[5];
  const float* be2 = (const float*)d_in[6];
  const float* ge2 = (const float*)d_in[7];
  const float* bne2 = (const float*)d_in[8];
  const float* Wd1 = (const float*)d_in[9];
  const float* bd1 = (const float*)d_in[10];
  const float* gd1 = (const float*)d_in[11];
  const float* bnd1 = (const float*)d_in[12];
  const float* Wd2 = (const float*)d_in[13];
  const float* bd2 = (const float*)d_in[14];
  const float* gd2 = (const float*)d_in[15];
  const float* bnd2 = (const float*)d_in[16];
  const float* codebook = (const float*)d_in[17];
  float* out = (float*)d_out;

  char* w = (char*)d_ws;
  auto alloc = [&](size_t bytes) -> char* {
    char* p = w;
    w += (bytes + 255) & ~(size_t)255;
    return p;
  };
  unsigned short* xb = (unsigned short*)alloc((size_t)8192 * 1024 * 2);
  unsigned short* wt0 = (unsigned short*)alloc((size_t)1024 * 1024 * 2);
  unsigned short* wt1 = (unsigned short*)alloc((size_t)1024 * 1024 * 2);
  unsigned short* wt2 = (unsigned short*)alloc((size_t)1024 * 1024 * 2);
  unsigned short* wt3 = (unsigned short*)alloc((size_t)1024 * 1024 * 2);
  unsigned short* cbb = (unsigned short*)alloc((size_t)8192 * 256 * 2);
  float* cnorm = (float*)alloc((size_t)8192 * 4);
  float* act = (float*)alloc((size_t)8192 * 1024 * 4);
  unsigned short* yb = (unsigned short*)alloc((size_t)8192 * 1024 * 2);
  unsigned short* zb = (unsigned short*)alloc((size_t)8192 * 1024 * 2);
  unsigned short* qb = (unsigned short*)alloc((size_t)8192 * 1024 * 2);
  unsigned long long* best = (unsigned long long*)alloc((size_t)32768 * 8);
  int* counts = (int*)alloc((size_t)8192 * 4);
  float* lpart = (float*)alloc((size_t)8192 * 4);

  hipMemsetAsync(counts, 0, (size_t)8192 * 4, stream);

  cast_bf16<<<(2097152 + 255) / 256, 256, 0, stream>>>(x, xb, 2097152);
  dim3 tg(32, 32);
  transpose_cast<<<tg, 256, 0, stream>>>(We1, wt0, 1024);
  transpose_cast<<<tg, 256, 0, stream>>>(We2, wt1, 1024);
  transpose_cast<<<tg, 256, 0, stream>>>(Wd1, wt2, 1024);
  transpose_cast<<<tg, 256, 0, stream>>>(Wd2, wt3, 1024);
  cast_bf16<<<(524288 + 255) / 256, 256, 0, stream>>>(codebook, cbb, 524288);
  code_norms<<<2048, 256, 0, stream>>>(codebook, cnorm);

  dim3 gg(8, 64);
  // encoder
  gemm_bias_relu<<<gg, 256, 0, stream>>>(xb, wt0, be1, act, 8192, 1024, 1024);
  ln_kernel<<<8192, 256, 0, stream>>>(act, ge1, bne1, yb, nullptr);
  gemm_bias_relu<<<gg, 256, 0, stream>>>(yb, wt1, be2, act, 8192, 1024, 1024);
  ln_kernel<<<8192, 256, 0, stream>>>(act, ge2, bne2, zb, nullptr);
  // VQ
  vq_dist<<<512, 256, 0, stream>>>(zb, cbb, cnorm, best);
  vq_gather<<<8192, 256, 0, stream>>>(best, codebook, zb, qb, counts, lpart);
  // decoder
  gemm_bias_relu<<<gg, 256, 0, stream>>>(qb, wt2, bd1, act, 8192, 1024, 1024);
  ln_kernel<<<8192, 256, 0, stream>>>(act, gd1, bnd1, yb, nullptr);
  gemm_bias_relu<<<gg, 256, 0, stream>>>(yb, wt3, bd2, act, 8192, 1024, 1024);
  ln_kernel<<<8192, 256, 0, stream>>>(act, gd2, bnd2, nullptr, out);

  finalize<<<1, 256, 0, stream>>>(counts, lpart, out + 8388608);
}

// Round 7
// 501.199 us; speedup vs baseline: 1.1467x; 1.1021x over previous
//
#include <hip/hip_runtime.h>
#include <stdint.h>

// ---------------------------------------------------------------------------
// VQ-VAE layer, all-bf16 MFMA pipeline.
// R6 -> R7: vq_dist's all-global-B design is structurally capped at ~27% MFMA
// (B demand 211 B/cyc/CU vs ~56 B/cyc/CU L2 supply). Dual-path operand feed:
// per 128-code chunk, codes [0,64) staged to LDS via double-buffered
// global_load_lds DMA (XOR-swizzled source, conflict-minimal b128 reads),
// codes [64,128) via direct global loads. Per ks-step: 1 ds_read_b128 +
// 1 global load + 8 MFMAs -> two ports feed the matrix pipe. One barrier per
// chunk (DMA issued a full chunk ahead). Also: GEMM writes bf16 C, LN reads
// bf16 (halves activation traffic).
// ---------------------------------------------------------------------------

typedef short bf16x8 __attribute__((ext_vector_type(8)));
typedef float f32x4 __attribute__((ext_vector_type(4)));

__device__ __forceinline__ void gl2lds16(const void* g, void* l) {
  __builtin_amdgcn_global_load_lds(
      (const __attribute__((address_space(1))) void*)g,
      (__attribute__((address_space(3))) void*)l, 16, 0, 0);
}

__device__ __forceinline__ float bf2f(unsigned short u) {
  return __uint_as_float(((unsigned)u) << 16);
}
__device__ __forceinline__ unsigned short f2bf(float f) {
  unsigned x = __float_as_uint(f);
  unsigned r = (x + 0x7fffu + ((x >> 16) & 1u)) >> 16;  // RNE
  return (unsigned short)r;
}
__device__ __forceinline__ unsigned long long packScore(float s, int code) {
  unsigned u = __float_as_uint(s);
  u = (u & 0x80000000u) ? ~u : (u | 0x80000000u);  // monotone map f32 -> u32
  return ((unsigned long long)u << 32) | (unsigned)code;
}
__device__ __forceinline__ unsigned long long shflxor_u64(unsigned long long v, int m) {
  union { unsigned long long u; int i[2]; } a;
  a.u = v;
  a.i[0] = __shfl_xor(a.i[0], m);
  a.i[1] = __shfl_xor(a.i[1], m);
  return a.u;
}

// ---------------------------------------------------------------------------
// cast fp32 -> bf16 (vectorized, n4 = count/4)
__global__ __launch_bounds__(256)
void cast_bf16(const float* __restrict__ X, unsigned short* __restrict__ Y, int n4) {
  int i = blockIdx.x * 256 + threadIdx.x;
  if (i < n4) {
    float4 v = ((const float4*)X)[i];
    ushort4 o = make_ushort4(f2bf(v.x), f2bf(v.y), f2bf(v.z), f2bf(v.w));
    ((ushort4*)Y)[i] = o;
  }
}

// transpose 1024x1024 fp32 W[i][j] -> bf16 Wt[j][i]
__global__ __launch_bounds__(256)
void transpose_cast(const float* __restrict__ W, unsigned short* __restrict__ Wt, int D) {
  __shared__ float s[32][33];
  int tx = threadIdx.x & 31, ty = threadIdx.x >> 5;  // 32x8
  int bx = blockIdx.x, by = blockIdx.y;
#pragma unroll
  for (int p = 0; p < 4; p++) {
    int r = by * 32 + ty + p * 8, c = bx * 32 + tx;
    s[ty + p * 8][tx] = W[(size_t)r * D + c];
  }
  __syncthreads();
#pragma unroll
  for (int p = 0; p < 4; p++) {
    int r = bx * 32 + ty + p * 8, c = by * 32 + tx;
    Wt[(size_t)r * D + c] = f2bf(s[tx][ty + p * 8]);
  }
}

// per-code squared norms (fp32), one wave per code row of 256
__global__ __launch_bounds__(256)
void code_norms(const float* __restrict__ cb, float* __restrict__ cn) {
  int row = blockIdx.x * 4 + (threadIdx.x >> 6);
  int lane = threadIdx.x & 63;
  float4 v = ((const float4*)(cb + (size_t)row * 256))[lane];
  float s = v.x * v.x + v.y * v.y + v.z * v.z + v.w * v.w;
#pragma unroll
  for (int off = 32; off > 0; off >>= 1) s += __shfl_down(s, off);
  if (lane == 0) cn[row] = s;
}

// ---------------------------------------------------------------------------
// GEMM: C[M,N] bf16 = relu(A[M,K]bf16 @ Bt[N,K]^T bf16 + bias)
// 128x128 tile, BK=64, DMA staging (global_load_lds w=16) + XOR swizzle.
__global__ __launch_bounds__(256, 2)
void gemm_bias_relu(const unsigned short* __restrict__ A, const unsigned short* __restrict__ Bt,
                    const float* __restrict__ bias, unsigned short* __restrict__ C,
                    int M, int N, int K) {
  __shared__ unsigned short As[128 * 64];
  __shared__ unsigned short Bs[128 * 64];
  const int t = threadIdx.x;
  const int wv = t >> 6, lane = t & 63;
  const int wm = wv >> 1, wn = wv & 1;
  const int quad = lane >> 4, l15 = lane & 15;
  const int row0 = blockIdx.y * 128, col0 = blockIdx.x * 128;
  const int rsub = lane >> 3;            // row within 8-row slab
  const int dchunk = (lane & 7) ^ rsub;  // xor-swizzled data chunk to fetch

  f32x4 acc[4][4];
#pragma unroll
  for (int i = 0; i < 4; i++)
#pragma unroll
    for (int j = 0; j < 4; j++) acc[i][j] = (f32x4){0.f, 0.f, 0.f, 0.f};

  for (int k0 = 0; k0 < K; k0 += 64) {
#pragma unroll
    for (int j = 0; j < 4; j++) {
      int slab = j * 4 + wv;            // 16 slabs of 8 rows (1024 B each)
      int row = slab * 8 + rsub;
      gl2lds16(A + (size_t)(row0 + row) * K + k0 + dchunk * 8, As + slab * 512);
      gl2lds16(Bt + (size_t)(col0 + row) * K + k0 + dchunk * 8, Bs + slab * 512);
    }
    __syncthreads();
#pragma unroll
    for (int kk = 0; kk < 2; kk++) {
      bf16x8 af[4], bfr[4];
#pragma unroll
      for (int mt = 0; mt < 4; mt++) {
        int row = wm * 64 + mt * 16 + l15;
        af[mt] = *(const bf16x8*)(As + row * 64 + (((kk * 4 + quad) ^ (l15 & 7)) * 8));
      }
#pragma unroll
      for (int nt = 0; nt < 4; nt++) {
        int row = wn * 64 + nt * 16 + l15;
        bfr[nt] = *(const bf16x8*)(Bs + row * 64 + (((kk * 4 + quad) ^ (l15 & 7)) * 8));
      }
#pragma unroll
      for (int mt = 0; mt < 4; mt++)
#pragma unroll
        for (int nt = 0; nt < 4; nt++)
          acc[mt][nt] = __builtin_amdgcn_mfma_f32_16x16x32_bf16(af[mt], bfr[nt], acc[mt][nt], 0, 0, 0);
    }
    __syncthreads();
  }
#pragma unroll
  for (int mt = 0; mt < 4; mt++) {
#pragma unroll
    for (int nt = 0; nt < 4; nt++) {
      int col = col0 + wn * 64 + nt * 16 + l15;
      float b = bias[col];
#pragma unroll
      for (int r = 0; r < 4; r++) {
        int row = row0 + wm * 64 + mt * 16 + quad * 4 + r;
        float v = acc[mt][nt][r] + b;
        C[(size_t)row * N + col] = f2bf(v > 0.f ? v : 0.f);
      }
    }
  }
}

// ---------------------------------------------------------------------------
// LayerNorm over rows of 1024 (bf16 in); writes bf16 (obf) or fp32 (of32)
__global__ __launch_bounds__(256)
void ln_kernel(const unsigned short* __restrict__ X, const float* __restrict__ g,
               const float* __restrict__ b, unsigned short* __restrict__ obf,
               float* __restrict__ of32) {
  const int row = blockIdx.x, t = threadIdx.x;
  ushort4 u = ((const ushort4*)(X + (size_t)row * 1024))[t];
  float4 v = make_float4(bf2f(u.x), bf2f(u.y), bf2f(u.z), bf2f(u.w));
  float s = v.x + v.y + v.z + v.w;
  float ss = v.x * v.x + v.y * v.y + v.z * v.z + v.w * v.w;
#pragma unroll
  for (int off = 32; off > 0; off >>= 1) {
    s += __shfl_down(s, off);
    ss += __shfl_down(ss, off);
  }
  __shared__ float rs[4], rss[4];
  const int wave = t >> 6, lane = t & 63;
  if (lane == 0) { rs[wave] = s; rss[wave] = ss; }
  __syncthreads();
  float S = rs[0] + rs[1] + rs[2] + rs[3];
  float SS = rss[0] + rss[1] + rss[2] + rss[3];
  float m = S * (1.0f / 1024.0f);
  float var = SS * (1.0f / 1024.0f) - m * m;
  float rstd = 1.0f / sqrtf(var + 1e-5f);
  float4 gv = ((const float4*)g)[t];
  float4 bv = ((const float4*)b)[t];
  float4 o;
  o.x = (v.x - m) * rstd * gv.x + bv.x;
  o.y = (v.y - m) * rstd * gv.y + bv.y;
  o.z = (v.z - m) * rstd * gv.z + bv.z;
  o.w = (v.w - m) * rstd * gv.w + bv.w;
  if (obf) {
    ushort4 q = make_ushort4(f2bf(o.x), f2bf(o.y), f2bf(o.z), f2bf(o.w));
    ((ushort4*)(obf + (size_t)row * 1024))[t] = q;
  } else {
    ((float4*)(of32 + (size_t)row * 1024))[t] = o;
  }
}

// ---------------------------------------------------------------------------
// VQ distance+argmin: Z[32768,256]bf16 vs Cb[8192,256]bf16.
// Block = 64 Z-rows x ALL 8192 codes (grid 512). Z register-resident zf[4][8].
// Per 128-code chunk: codes [0,64) DMA-staged to LDS (dbuf, XOR swizzle),
// codes [64,128) direct global. Per ks: 1 ds_read_b128 + 1 global + 8 MFMAs.
__global__ __launch_bounds__(256, 2)
void vq_dist(const unsigned short* __restrict__ Z, const unsigned short* __restrict__ Cb,
             const float* __restrict__ cnorm, unsigned long long* __restrict__ bestg) {
  __shared__ unsigned short Bs[2][64 * 256];  // 2 x 32KB
  __shared__ unsigned long long runmin[64];
  const int t = threadIdx.x;
  const int wv = t >> 6, lane = t & 63;
  const int quad = lane >> 4, l15 = lane & 15;
  const int row0 = blockIdx.x * 64;

  if (t < 64) runmin[t] = ~0ull;

  // Z fragments for this wave: rows mt*16+l15, K-step ks (8 bf16 each)
  bf16x8 zf[4][8];
#pragma unroll
  for (int mt = 0; mt < 4; mt++)
#pragma unroll
    for (int ks = 0; ks < 8; ks++)
      zf[mt][ks] = *(const bf16x8*)(Z + (size_t)(row0 + mt * 16 + l15) * 256 + ks * 32 + quad * 8);

  float msc[4][4];
  int mcd[4][4];
#pragma unroll
  for (int mt = 0; mt < 4; mt++)
#pragma unroll
    for (int r = 0; r < 4; r++) { msc[mt][r] = 3.4e38f; mcd[mt][r] = 0; }

  // DMA staging: chunk ch codes [ch*128, ch*128+64) -> Bs[b], 32 slabs of 1KB.
  // lane writes LDS slab*1024 + lane*16; source granule XOR-swizzled by code&7.
  const int dcode = lane >> 5;  // 0/1 within slab
  const int dgr = lane & 31;

  // global-half: codes ch*128 + 64 + wv*16 + l15, dims ks*32+quad*8
  const unsigned short* gbase = Cb + (size_t)(64 + wv * 16 + l15) * 256 + quad * 8;
  // LDS-half read: slot = wv*16+l15, granule (ks*4+quad)^(slot&7)
  const int slot = wv * 16 + l15;
  const int rxor = l15 & 7;

  // stage chunk 0 into Bs[0]
#pragma unroll
  for (int j = 0; j < 8; j++) {
    int slab = wv * 8 + j;
    int sl = slab * 2 + dcode;
    gl2lds16(Cb + (size_t)sl * 256 + ((dgr ^ (sl & 7)) * 8), &Bs[0][slab * 512]);
  }
  bf16x8 gbuf[2];
  gbuf[0] = *(const bf16x8*)(gbase);  // ch=0, ks=0
  __syncthreads();                    // chunk-0 DMA complete

  for (int ch = 0; ch < 64; ch++) {
    const int cur = ch & 1;
    if (ch + 1 < 64) {
      const int cb2 = (ch + 1) * 128;
#pragma unroll
      for (int j = 0; j < 8; j++) {
        int slab = wv * 8 + j;
        int sl = slab * 2 + dcode;
        gl2lds16(Cb + (size_t)(cb2 + sl) * 256 + ((dgr ^ (sl & 7)) * 8),
                 &Bs[cur ^ 1][slab * 512]);
      }
    }
    float cn0 = cnorm[ch * 128 + slot];
    float cn1 = cnorm[ch * 128 + 64 + slot];

    bf16x8 lbuf[2];
    lbuf[0] = *(const bf16x8*)(&Bs[cur][slot * 256 + ((quad ^ rxor) * 8)]);

    f32x4 acc[4][2];
#pragma unroll
    for (int ks = 0; ks < 8; ks++) {
      if (ks < 7)
        lbuf[(ks + 1) & 1] =
            *(const bf16x8*)(&Bs[cur][slot * 256 + ((((ks + 1) * 4 + quad) ^ rxor) * 8)]);
      {
        const size_t noff = (ks == 7) ? (size_t)((ch + 1) & 63) * 32768
                                      : (size_t)ch * 32768 + (size_t)(ks + 1) * 32;
        gbuf[(ks + 1) & 1] = *(const bf16x8*)(gbase + noff);
      }
      bf16x8 lb = lbuf[ks & 1], gb = gbuf[ks & 1];
      if (ks == 0) {
        const f32x4 z4 = (f32x4){0.f, 0.f, 0.f, 0.f};
#pragma unroll
        for (int mt = 0; mt < 4; mt++) {
          acc[mt][0] = __builtin_amdgcn_mfma_f32_16x16x32_bf16(zf[mt][0], lb, z4, 0, 0, 0);
          acc[mt][1] = __builtin_amdgcn_mfma_f32_16x16x32_bf16(zf[mt][0], gb, z4, 0, 0, 0);
        }
      } else {
#pragma unroll
        for (int mt = 0; mt < 4; mt++) {
          acc[mt][0] = __builtin_amdgcn_mfma_f32_16x16x32_bf16(zf[mt][ks], lb, acc[mt][0], 0, 0, 0);
          acc[mt][1] = __builtin_amdgcn_mfma_f32_16x16x32_bf16(zf[mt][ks], gb, acc[mt][1], 0, 0, 0);
        }
      }
    }
    // argmin update; per-lane visit order ascending (ch asc, p asc) ->
    // strict < keeps lowest index (reference tie-break)
#pragma unroll
    for (int p = 0; p < 2; p++) {
      int code = ch * 128 + p * 64 + slot;
      float cn = p == 0 ? cn0 : cn1;
#pragma unroll
      for (int mt = 0; mt < 4; mt++)
#pragma unroll
        for (int r = 0; r < 4; r++) {
          float sc = cn - 2.0f * acc[mt][p][r];
          if (sc < msc[mt][r]) { msc[mt][r] = sc; mcd[mt][r] = code; }
        }
    }
    __syncthreads();  // next chunk's DMA visible; all reads of Bs[cur] done
  }

#pragma unroll
  for (int mt = 0; mt < 4; mt++) {
#pragma unroll
    for (int r = 0; r < 4; r++) {
      unsigned long long bp = packScore(msc[mt][r], mcd[mt][r]);
#pragma unroll
      for (int m = 1; m < 16; m <<= 1) {
        unsigned long long o = shflxor_u64(bp, m);
        bp = o < bp ? o : bp;
      }
      if (l15 == 0) atomicMin(&runmin[mt * 16 + quad * 4 + r], bp);
    }
  }
  __syncthreads();
  if (t < 64) bestg[row0 + t] = runmin[t];  // block owns these rows exclusively
}

// ---------------------------------------------------------------------------
// gather quantized rows (bf16 for decoder), histogram, per-block loss partial
__global__ __launch_bounds__(256)
void vq_gather(const unsigned long long* __restrict__ bestg, const float* __restrict__ cb,
               const unsigned short* __restrict__ zb, unsigned short* __restrict__ qb,
               int* __restrict__ counts, float* __restrict__ lpart) {
  const int wave = threadIdx.x >> 6;
  const int g = blockIdx.x * 4 + wave;
  const int lane = threadIdx.x & 63;
  const int idx = (int)(bestg[g] & 0xFFFFFFFFull);
  float4 c = ((const float4*)(cb + (size_t)idx * 256))[lane];
  ushort4 q = make_ushort4(f2bf(c.x), f2bf(c.y), f2bf(c.z), f2bf(c.w));
  ((ushort4*)(qb + (size_t)g * 256))[lane] = q;
  ushort4 z = ((const ushort4*)(zb + (size_t)g * 256))[lane];
  float dx = c.x - bf2f(z.x), dy = c.y - bf2f(z.y);
  float dz = c.z - bf2f(z.z), dw = c.w - bf2f(z.w);
  float p = dx * dx + dy * dy + dz * dz + dw * dw;
#pragma unroll
  for (int off = 32; off > 0; off >>= 1) p += __shfl_down(p, off);
  __shared__ float sp[4];
  if (lane == 0) {
    sp[wave] = p;
    atomicAdd(&counts[idx], 1);
  }
  __syncthreads();
  if (threadIdx.x == 0) lpart[blockIdx.x] = sp[0] + sp[1] + sp[2] + sp[3];
}

// loss + perplexity scalars
__global__ __launch_bounds__(256)
void finalize(const int* __restrict__ counts, const float* __restrict__ lpart,
              float* __restrict__ out2) {
  const int t = threadIdx.x;
  double h = 0.0, l = 0.0;
  for (int i = t; i < 8192; i += 256) {
    double pr = (double)counts[i] * (1.0 / 32768.0);
    h += pr * log(pr + 1e-10);
    l += (double)lpart[i];
  }
  __shared__ double sh[256], sl[256];
  sh[t] = h;
  sl[t] = l;
  __syncthreads();
  for (int w = 128; w > 0; w >>= 1) {
    if (t < w) { sh[t] += sh[t + w]; sl[t] += sl[t + w]; }
    __syncthreads();
  }
  if (t == 0) {
    out2[0] = (float)(1.25 * sl[0] * (1.0 / 8388608.0));
    out2[1] = (float)exp(-sh[0]);
  }
}

// ---------------------------------------------------------------------------
extern "C" void kernel_launch(void* const* d_in, const int* in_sizes, int n_in,
                              void* d_out, int out_size, void* d_ws, size_t ws_size,
                              hipStream_t stream) {
  const float* x = (const float*)d_in[0];
  const float* We1 = (const float*)d_in[1];
  const float* be1 = (const float*)d_in[2];
  const float* ge1 = (const float*)d_in[3];
  const float* bne1 = (const float*)d_in[4];
  const float* We2 = (const float*)d_in[5];
  const float* be2 = (const float*)d_in[6];
  const float* ge2 = (const float*)d_in[7];
  const float* bne2 = (const float*)d_in[8];
  const float* Wd1 = (const float*)d_in[9];
  const float* bd1 = (const float*)d_in[10];
  const float* gd1 = (const float*)d_in[11];
  const float* bnd1 = (const float*)d_in[12];
  const float* Wd2 = (const float*)d_in[13];
  const float* bd2 = (const float*)d_in[14];
  const float* gd2 = (const float*)d_in[15];
  const float* bnd2 = (const float*)d_in[16];
  const float* codebook = (const float*)d_in[17];
  float* out = (float*)d_out;

  char* w = (char*)d_ws;
  auto alloc = [&](size_t bytes) -> char* {
    char* p = w;
    w += (bytes + 255) & ~(size_t)255;
    return p;
  };
  unsigned short* xb = (unsigned short*)alloc((size_t)8192 * 1024 * 2);
  unsigned short* wt0 = (unsigned short*)alloc((size_t)1024 * 1024 * 2);
  unsigned short* wt1 = (unsigned short*)alloc((size_t)1024 * 1024 * 2);
  unsigned short* wt2 = (unsigned short*)alloc((size_t)1024 * 1024 * 2);
  unsigned short* wt3 = (unsigned short*)alloc((size_t)1024 * 1024 * 2);
  unsigned short* cbb = (unsigned short*)alloc((size_t)8192 * 256 * 2);
  float* cnorm = (float*)alloc((size_t)8192 * 4);
  unsigned short* act = (unsigned short*)alloc((size_t)8192 * 1024 * 2);
  unsigned short* yb = (unsigned short*)alloc((size_t)8192 * 1024 * 2);
  unsigned short* zb = (unsigned short*)alloc((size_t)8192 * 1024 * 2);
  unsigned short* qb = (unsigned short*)alloc((size_t)8192 * 1024 * 2);
  unsigned long long* best = (unsigned long long*)alloc((size_t)32768 * 8);
  int* counts = (int*)alloc((size_t)8192 * 4);
  float* lpart = (float*)alloc((size_t)8192 * 4);

  hipMemsetAsync(counts, 0, (size_t)8192 * 4, stream);

  cast_bf16<<<(2097152 + 255) / 256, 256, 0, stream>>>(x, xb, 2097152);
  dim3 tg(32, 32);
  transpose_cast<<<tg, 256, 0, stream>>>(We1, wt0, 1024);
  transpose_cast<<<tg, 256, 0, stream>>>(We2, wt1, 1024);
  transpose_cast<<<tg, 256, 0, stream>>>(Wd1, wt2, 1024);
  transpose_cast<<<tg, 256, 0, stream>>>(Wd2, wt3, 1024);
  cast_bf16<<<(524288 + 255) / 256, 256, 0, stream>>>(codebook, cbb, 524288);
  code_norms<<<2048, 256, 0, stream>>>(codebook, cnorm);

  dim3 gg(8, 64);
  // encoder
  gemm_bias_relu<<<gg, 256, 0, stream>>>(xb, wt0, be1, act, 8192, 1024, 1024);
  ln_kernel<<<8192, 256, 0, stream>>>(act, ge1, bne1, yb, nullptr);
  gemm_bias_relu<<<gg, 256, 0, stream>>>(yb, wt1, be2, act, 8192, 1024, 1024);
  ln_kernel<<<8192, 256, 0, stream>>>(act, ge2, bne2, zb, nullptr);
  // VQ
  vq_dist<<<512, 256, 0, stream>>>(zb, cbb, cnorm, best);
  vq_gather<<<8192, 256, 0, stream>>>(best, codebook, zb, qb, counts, lpart);
  // decoder
  gemm_bias_relu<<<gg, 256, 0, stream>>>(qb, wt2, bd1, act, 8192, 1024, 1024);
  ln_kernel<<<8192, 256, 0, stream>>>(act, gd1, bnd1, yb, nullptr);
  gemm_bias_relu<<<gg, 256, 0, stream>>>(yb, wt3, bd2, act, 8192, 1024, 1024);
  ln_kernel<<<8192, 256, 0, stream>>>(act, gd2, bnd2, nullptr, out);

  finalize<<<1, 256, 0, stream>>>(counts, lpart, out + 8388608);
}

// Round 8
// 470.433 us; speedup vs baseline: 1.2216x; 1.0654x over previous
//
#include <hip/hip_runtime.h>
#include <stdint.h>

// ---------------------------------------------------------------------------
// VQ-VAE layer, all-bf16 MFMA pipeline.
// R7 -> R8: vq_dist's per-chunk __syncthreads was the residual stall (chunk
// wall 7900 cyc vs ~2500 cyc MFMA/L2 budget; barrier = vmcnt(0) drain + all 8
// waves/CU phase-locked). The LDS staging is WAVE-PRIVATE (wave wv DMAs slabs
// [8wv,8wv+8) and reads only slots [16wv,16wv+16)), so no cross-wave barrier
// is needed: replace both barriers with a per-wave s_waitcnt vmcnt(0)
// (imm 0x3F70; lgkm/exp no-wait) at chunk top -- waves free-run and hide each
// other's latency (AITER-style fine-grained wait, never a block barrier).
// ---------------------------------------------------------------------------

typedef short bf16x8 __attribute__((ext_vector_type(8)));
typedef float f32x4 __attribute__((ext_vector_type(4)));

__device__ __forceinline__ void gl2lds16(const void* g, void* l) {
  __builtin_amdgcn_global_load_lds(
      (const __attribute__((address_space(1))) void*)g,
      (__attribute__((address_space(3))) void*)l, 16, 0, 0);
}

__device__ __forceinline__ float bf2f(unsigned short u) {
  return __uint_as_float(((unsigned)u) << 16);
}
__device__ __forceinline__ unsigned short f2bf(float f) {
  unsigned x = __float_as_uint(f);
  unsigned r = (x + 0x7fffu + ((x >> 16) & 1u)) >> 16;  // RNE
  return (unsigned short)r;
}
__device__ __forceinline__ unsigned long long packScore(float s, int code) {
  unsigned u = __float_as_uint(s);
  u = (u & 0x80000000u) ? ~u : (u | 0x80000000u);  // monotone map f32 -> u32
  return ((unsigned long long)u << 32) | (unsigned)code;
}
__device__ __forceinline__ unsigned long long shflxor_u64(unsigned long long v, int m) {
  union { unsigned long long u; int i[2]; } a;
  a.u = v;
  a.i[0] = __shfl_xor(a.i[0], m);
  a.i[1] = __shfl_xor(a.i[1], m);
  return a.u;
}

// ---------------------------------------------------------------------------
// cast fp32 -> bf16 (vectorized, n4 = count/4)
__global__ __launch_bounds__(256)
void cast_bf16(const float* __restrict__ X, unsigned short* __restrict__ Y, int n4) {
  int i = blockIdx.x * 256 + threadIdx.x;
  if (i < n4) {
    float4 v = ((const float4*)X)[i];
    ushort4 o = make_ushort4(f2bf(v.x), f2bf(v.y), f2bf(v.z), f2bf(v.w));
    ((ushort4*)Y)[i] = o;
  }
}

// transpose 1024x1024 fp32 W[i][j] -> bf16 Wt[j][i]
__global__ __launch_bounds__(256)
void transpose_cast(const float* __restrict__ W, unsigned short* __restrict__ Wt, int D) {
  __shared__ float s[32][33];
  int tx = threadIdx.x & 31, ty = threadIdx.x >> 5;  // 32x8
  int bx = blockIdx.x, by = blockIdx.y;
#pragma unroll
  for (int p = 0; p < 4; p++) {
    int r = by * 32 + ty + p * 8, c = bx * 32 + tx;
    s[ty + p * 8][tx] = W[(size_t)r * D + c];
  }
  __syncthreads();
#pragma unroll
  for (int p = 0; p < 4; p++) {
    int r = bx * 32 + ty + p * 8, c = by * 32 + tx;
    Wt[(size_t)r * D + c] = f2bf(s[tx][ty + p * 8]);
  }
}

// per-code squared norms (fp32), one wave per code row of 256
__global__ __launch_bounds__(256)
void code_norms(const float* __restrict__ cb, float* __restrict__ cn) {
  int row = blockIdx.x * 4 + (threadIdx.x >> 6);
  int lane = threadIdx.x & 63;
  float4 v = ((const float4*)(cb + (size_t)row * 256))[lane];
  float s = v.x * v.x + v.y * v.y + v.z * v.z + v.w * v.w;
#pragma unroll
  for (int off = 32; off > 0; off >>= 1) s += __shfl_down(s, off);
  if (lane == 0) cn[row] = s;
}

// ---------------------------------------------------------------------------
// GEMM: C[M,N] bf16 = relu(A[M,K]bf16 @ Bt[N,K]^T bf16 + bias)
// 128x128 tile, BK=64, DMA staging (global_load_lds w=16) + XOR swizzle.
__global__ __launch_bounds__(256, 2)
void gemm_bias_relu(const unsigned short* __restrict__ A, const unsigned short* __restrict__ Bt,
                    const float* __restrict__ bias, unsigned short* __restrict__ C,
                    int M, int N, int K) {
  __shared__ unsigned short As[128 * 64];
  __shared__ unsigned short Bs[128 * 64];
  const int t = threadIdx.x;
  const int wv = t >> 6, lane = t & 63;
  const int wm = wv >> 1, wn = wv & 1;
  const int quad = lane >> 4, l15 = lane & 15;
  const int row0 = blockIdx.y * 128, col0 = blockIdx.x * 128;
  const int rsub = lane >> 3;            // row within 8-row slab
  const int dchunk = (lane & 7) ^ rsub;  // xor-swizzled data chunk to fetch

  f32x4 acc[4][4];
#pragma unroll
  for (int i = 0; i < 4; i++)
#pragma unroll
    for (int j = 0; j < 4; j++) acc[i][j] = (f32x4){0.f, 0.f, 0.f, 0.f};

  for (int k0 = 0; k0 < K; k0 += 64) {
#pragma unroll
    for (int j = 0; j < 4; j++) {
      int slab = j * 4 + wv;            // 16 slabs of 8 rows (1024 B each)
      int row = slab * 8 + rsub;
      gl2lds16(A + (size_t)(row0 + row) * K + k0 + dchunk * 8, As + slab * 512);
      gl2lds16(Bt + (size_t)(col0 + row) * K + k0 + dchunk * 8, Bs + slab * 512);
    }
    __syncthreads();
#pragma unroll
    for (int kk = 0; kk < 2; kk++) {
      bf16x8 af[4], bfr[4];
#pragma unroll
      for (int mt = 0; mt < 4; mt++) {
        int row = wm * 64 + mt * 16 + l15;
        af[mt] = *(const bf16x8*)(As + row * 64 + (((kk * 4 + quad) ^ (l15 & 7)) * 8));
      }
#pragma unroll
      for (int nt = 0; nt < 4; nt++) {
        int row = wn * 64 + nt * 16 + l15;
        bfr[nt] = *(const bf16x8*)(Bs + row * 64 + (((kk * 4 + quad) ^ (l15 & 7)) * 8));
      }
#pragma unroll
      for (int mt = 0; mt < 4; mt++)
#pragma unroll
        for (int nt = 0; nt < 4; nt++)
          acc[mt][nt] = __builtin_amdgcn_mfma_f32_16x16x32_bf16(af[mt], bfr[nt], acc[mt][nt], 0, 0, 0);
    }
    __syncthreads();
  }
#pragma unroll
  for (int mt = 0; mt < 4; mt++) {
#pragma unroll
    for (int nt = 0; nt < 4; nt++) {
      int col = col0 + wn * 64 + nt * 16 + l15;
      float b = bias[col];
#pragma unroll
      for (int r = 0; r < 4; r++) {
        int row = row0 + wm * 64 + mt * 16 + quad * 4 + r;
        float v = acc[mt][nt][r] + b;
        C[(size_t)row * N + col] = f2bf(v > 0.f ? v : 0.f);
      }
    }
  }
}

// ---------------------------------------------------------------------------
// LayerNorm over rows of 1024 (bf16 in); writes bf16 (obf) or fp32 (of32)
__global__ __launch_bounds__(256)
void ln_kernel(const unsigned short* __restrict__ X, const float* __restrict__ g,
               const float* __restrict__ b, unsigned short* __restrict__ obf,
               float* __restrict__ of32) {
  const int row = blockIdx.x, t = threadIdx.x;
  ushort4 u = ((const ushort4*)(X + (size_t)row * 1024))[t];
  float4 v = make_float4(bf2f(u.x), bf2f(u.y), bf2f(u.z), bf2f(u.w));
  float s = v.x + v.y + v.z + v.w;
  float ss = v.x * v.x + v.y * v.y + v.z * v.z + v.w * v.w;
#pragma unroll
  for (int off = 32; off > 0; off >>= 1) {
    s += __shfl_down(s, off);
    ss += __shfl_down(ss, off);
  }
  __shared__ float rs[4], rss[4];
  const int wave = t >> 6, lane = t & 63;
  if (lane == 0) { rs[wave] = s; rss[wave] = ss; }
  __syncthreads();
  float S = rs[0] + rs[1] + rs[2] + rs[3];
  float SS = rss[0] + rss[1] + rss[2] + rss[3];
  float m = S * (1.0f / 1024.0f);
  float var = SS * (1.0f / 1024.0f) - m * m;
  float rstd = 1.0f / sqrtf(var + 1e-5f);
  float4 gv = ((const float4*)g)[t];
  float4 bv = ((const float4*)b)[t];
  float4 o;
  o.x = (v.x - m) * rstd * gv.x + bv.x;
  o.y = (v.y - m) * rstd * gv.y + bv.y;
  o.z = (v.z - m) * rstd * gv.z + bv.z;
  o.w = (v.w - m) * rstd * gv.w + bv.w;
  if (obf) {
    ushort4 q = make_ushort4(f2bf(o.x), f2bf(o.y), f2bf(o.z), f2bf(o.w));
    ((ushort4*)(obf + (size_t)row * 1024))[t] = q;
  } else {
    ((float4*)(of32 + (size_t)row * 1024))[t] = o;
  }
}

// ---------------------------------------------------------------------------
// VQ distance+argmin: Z[32768,256]bf16 vs Cb[8192,256]bf16.
// Block = 64 Z-rows x ALL 8192 codes (grid 512). Z register-resident zf[4][8].
// Per 128-code chunk: codes [0,64) DMA-staged to LDS (dbuf, XOR swizzle,
// WAVE-PRIVATE slabs), codes [64,128) direct global. NO barriers in the main
// loop -- per-wave s_waitcnt vmcnt(0) at chunk top guards the wave's own DMA.
__global__ __launch_bounds__(256, 2)
void vq_dist(const unsigned short* __restrict__ Z, const unsigned short* __restrict__ Cb,
             const float* __restrict__ cnorm, unsigned long long* __restrict__ bestg) {
  __shared__ unsigned short Bs[2][64 * 256];  // 2 x 32KB
  __shared__ unsigned long long runmin[64];
  const int t = threadIdx.x;
  const int wv = t >> 6, lane = t & 63;
  const int quad = lane >> 4, l15 = lane & 15;
  const int row0 = blockIdx.x * 64;

  if (t < 64) runmin[t] = ~0ull;

  // Z fragments for this wave: rows mt*16+l15, K-step ks (8 bf16 each)
  bf16x8 zf[4][8];
#pragma unroll
  for (int mt = 0; mt < 4; mt++)
#pragma unroll
    for (int ks = 0; ks < 8; ks++)
      zf[mt][ks] = *(const bf16x8*)(Z + (size_t)(row0 + mt * 16 + l15) * 256 + ks * 32 + quad * 8);

  float msc[4][4];
  int mcd[4][4];
#pragma unroll
  for (int mt = 0; mt < 4; mt++)
#pragma unroll
    for (int r = 0; r < 4; r++) { msc[mt][r] = 3.4e38f; mcd[mt][r] = 0; }

  // DMA staging: chunk ch codes [ch*128, ch*128+64) -> Bs[b], 32 slabs of 1KB.
  // Wave wv stages slabs [8wv, 8wv+8) == exactly the slots it reads below.
  const int dcode = lane >> 5;  // 0/1 within slab
  const int dgr = lane & 31;

  // global-half: codes ch*128 + 64 + wv*16 + l15, dims ks*32+quad*8
  const unsigned short* gbase = Cb + (size_t)(64 + wv * 16 + l15) * 256 + quad * 8;
  // LDS-half read: slot = wv*16+l15, granule (ks*4+quad)^(slot&7)
  const int slot = wv * 16 + l15;
  const int rxor = l15 & 7;

  // stage chunk 0 into Bs[0]
#pragma unroll
  for (int j = 0; j < 8; j++) {
    int slab = wv * 8 + j;
    int sl = slab * 2 + dcode;
    gl2lds16(Cb + (size_t)sl * 256 + ((dgr ^ (sl & 7)) * 8), &Bs[0][slab * 512]);
  }
  bf16x8 gbuf[2];
  gbuf[0] = *(const bf16x8*)(gbase);  // ch=0, ks=0

  for (int ch = 0; ch < 64; ch++) {
    // wait for THIS wave's outstanding vmem (incl. its DMA for chunk ch);
    // lgkm/exp not waited. Waves stay unsynchronized.
    __builtin_amdgcn_s_waitcnt(0x3F70);

    const int cur = ch & 1;
    if (ch + 1 < 64) {
      const int cb2 = (ch + 1) * 128;
#pragma unroll
      for (int j = 0; j < 8; j++) {
        int slab = wv * 8 + j;
        int sl = slab * 2 + dcode;
        gl2lds16(Cb + (size_t)(cb2 + sl) * 256 + ((dgr ^ (sl & 7)) * 8),
                 &Bs[cur ^ 1][slab * 512]);
      }
    }
    float cn0 = cnorm[ch * 128 + slot];
    float cn1 = cnorm[ch * 128 + 64 + slot];

    bf16x8 lbuf[2];
    lbuf[0] = *(const bf16x8*)(&Bs[cur][slot * 256 + ((quad ^ rxor) * 8)]);

    f32x4 acc[4][2];
#pragma unroll
    for (int ks = 0; ks < 8; ks++) {
      if (ks < 7)
        lbuf[(ks + 1) & 1] =
            *(const bf16x8*)(&Bs[cur][slot * 256 + ((((ks + 1) * 4 + quad) ^ rxor) * 8)]);
      {
        const size_t noff = (ks == 7) ? (size_t)((ch + 1) & 63) * 32768
                                      : (size_t)ch * 32768 + (size_t)(ks + 1) * 32;
        gbuf[(ks + 1) & 1] = *(const bf16x8*)(gbase + noff);
      }
      bf16x8 lb = lbuf[ks & 1], gb = gbuf[ks & 1];
      if (ks == 0) {
        const f32x4 z4 = (f32x4){0.f, 0.f, 0.f, 0.f};
#pragma unroll
        for (int mt = 0; mt < 4; mt++) {
          acc[mt][0] = __builtin_amdgcn_mfma_f32_16x16x32_bf16(zf[mt][0], lb, z4, 0, 0, 0);
          acc[mt][1] = __builtin_amdgcn_mfma_f32_16x16x32_bf16(zf[mt][0], gb, z4, 0, 0, 0);
        }
      } else {
#pragma unroll
        for (int mt = 0; mt < 4; mt++) {
          acc[mt][0] = __builtin_amdgcn_mfma_f32_16x16x32_bf16(zf[mt][ks], lb, acc[mt][0], 0, 0, 0);
          acc[mt][1] = __builtin_amdgcn_mfma_f32_16x16x32_bf16(zf[mt][ks], gb, acc[mt][1], 0, 0, 0);
        }
      }
    }
    // argmin update; per-lane visit order ascending (ch asc, p asc) ->
    // strict < keeps lowest index (reference tie-break)
#pragma unroll
    for (int p = 0; p < 2; p++) {
      int code = ch * 128 + p * 64 + slot;
      float cn = p == 0 ? cn0 : cn1;
#pragma unroll
      for (int mt = 0; mt < 4; mt++)
#pragma unroll
        for (int r = 0; r < 4; r++) {
          float sc = cn - 2.0f * acc[mt][p][r];
          if (sc < msc[mt][r]) { msc[mt][r] = sc; mcd[mt][r] = code; }
        }
    }
  }

  __syncthreads();  // runmin init visible; all waves done before merge
#pragma unroll
  for (int mt = 0; mt < 4; mt++) {
#pragma unroll
    for (int r = 0; r < 4; r++) {
      unsigned long long bp = packScore(msc[mt][r], mcd[mt][r]);
#pragma unroll
      for (int m = 1; m < 16; m <<= 1) {
        unsigned long long o = shflxor_u64(bp, m);
        bp = o < bp ? o : bp;
      }
      if (l15 == 0) atomicMin(&runmin[mt * 16 + quad * 4 + r], bp);
    }
  }
  __syncthreads();
  if (t < 64) bestg[row0 + t] = runmin[t];  // block owns these rows exclusively
}

// ---------------------------------------------------------------------------
// gather quantized rows (bf16 for decoder), histogram, per-block loss partial
__global__ __launch_bounds__(256)
void vq_gather(const unsigned long long* __restrict__ bestg, const float* __restrict__ cb,
               const unsigned short* __restrict__ zb, unsigned short* __restrict__ qb,
               int* __restrict__ counts, float* __restrict__ lpart) {
  const int wave = threadIdx.x >> 6;
  const int g = blockIdx.x * 4 + wave;
  const int lane = threadIdx.x & 63;
  const int idx = (int)(bestg[g] & 0xFFFFFFFFull);
  float4 c = ((const float4*)(cb + (size_t)idx * 256))[lane];
  ushort4 q = make_ushort4(f2bf(c.x), f2bf(c.y), f2bf(c.z), f2bf(c.w));
  ((ushort4*)(qb + (size_t)g * 256))[lane] = q;
  ushort4 z = ((const ushort4*)(zb + (size_t)g * 256))[lane];
  float dx = c.x - bf2f(z.x), dy = c.y - bf2f(z.y);
  float dz = c.z - bf2f(z.z), dw = c.w - bf2f(z.w);
  float p = dx * dx + dy * dy + dz * dz + dw * dw;
#pragma unroll
  for (int off = 32; off > 0; off >>= 1) p += __shfl_down(p, off);
  __shared__ float sp[4];
  if (lane == 0) {
    sp[wave] = p;
    atomicAdd(&counts[idx], 1);
  }
  __syncthreads();
  if (threadIdx.x == 0) lpart[blockIdx.x] = sp[0] + sp[1] + sp[2] + sp[3];
}

// loss + perplexity scalars
__global__ __launch_bounds__(256)
void finalize(const int* __restrict__ counts, const float* __restrict__ lpart,
              float* __restrict__ out2) {
  const int t = threadIdx.x;
  double h = 0.0, l = 0.0;
  for (int i = t; i < 8192; i += 256) {
    double pr = (double)counts[i] * (1.0 / 32768.0);
    h += pr * log(pr + 1e-10);
    l += (double)lpart[i];
  }
  __shared__ double sh[256], sl[256];
  sh[t] = h;
  sl[t] = l;
  __syncthreads();
  for (int w = 128; w > 0; w >>= 1) {
    if (t < w) { sh[t] += sh[t + w]; sl[t] += sl[t + w]; }
    __syncthreads();
  }
  if (t == 0) {
    out2[0] = (float)(1.25 * sl[0] * (1.0 / 8388608.0));
    out2[1] = (float)exp(-sh[0]);
  }
}

// ---------------------------------------------------------------------------
extern "C" void kernel_launch(void* const* d_in, const int* in_sizes, int n_in,
                              void* d_out, int out_size, void* d_ws, size_t ws_size,
                              hipStream_t stream) {
  const float* x = (const float*)d_in[0];
  const float* We1 = (const float*)d_in[1];
  const float* be1 = (const float*)d_in[2];
  const float* ge1 = (const float*)d_in[3];
  const float* bne1 = (const float*)d_in[4];
  const float* We2 = (const float*)d_in[5];
  const float* be2 = (const float*)d_in[6];
  const float* ge2 = (const float*)d_in[7];
  const float* bne2 = (const float*)d_in[8];
  const float* Wd1 = (const float*)d_in[9];
  const float* bd1 = (const float*)d_in[10];
  const float* gd1 = (const float*)d_in[11];
  const float* bnd1 = (const float*)d_in[12];
  const float* Wd2 = (const float*)d_in[13];
  const float* bd2 = (const float*)d_in[14];
  const float* gd2 = (const float*)d_in[15];
  const float* bnd2 = (const float*)d_in[16];
  const float* codebook = (const float*)d_in[17];
  float* out = (float*)d_out;

  char* w = (char*)d_ws;
  auto alloc = [&](size_t bytes) -> char* {
    char* p = w;
    w += (bytes + 255) & ~(size_t)255;
    return p;
  };
  unsigned short* xb = (unsigned short*)alloc((size_t)8192 * 1024 * 2);
  unsigned short* wt0 = (unsigned short*)alloc((size_t)1024 * 1024 * 2);
  unsigned short* wt1 = (unsigned short*)alloc((size_t)1024 * 1024 * 2);
  unsigned short* wt2 = (unsigned short*)alloc((size_t)1024 * 1024 * 2);
  unsigned short* wt3 = (unsigned short*)alloc((size_t)1024 * 1024 * 2);
  unsigned short* cbb = (unsigned short*)alloc((size_t)8192 * 256 * 2);
  float* cnorm = (float*)alloc((size_t)8192 * 4);
  unsigned short* act = (unsigned short*)alloc((size_t)8192 * 1024 * 2);
  unsigned short* yb = (unsigned short*)alloc((size_t)8192 * 1024 * 2);
  unsigned short* zb = (unsigned short*)alloc((size_t)8192 * 1024 * 2);
  unsigned short* qb = (unsigned short*)alloc((size_t)8192 * 1024 * 2);
  unsigned long long* best = (unsigned long long*)alloc((size_t)32768 * 8);
  int* counts = (int*)alloc((size_t)8192 * 4);
  float* lpart = (float*)alloc((size_t)8192 * 4);

  hipMemsetAsync(counts, 0, (size_t)8192 * 4, stream);

  cast_bf16<<<(2097152 + 255) / 256, 256, 0, stream>>>(x, xb, 2097152);
  dim3 tg(32, 32);
  transpose_cast<<<tg, 256, 0, stream>>>(We1, wt0, 1024);
  transpose_cast<<<tg, 256, 0, stream>>>(We2, wt1, 1024);
  transpose_cast<<<tg, 256, 0, stream>>>(Wd1, wt2, 1024);
  transpose_cast<<<tg, 256, 0, stream>>>(Wd2, wt3, 1024);
  cast_bf16<<<(524288 + 255) / 256, 256, 0, stream>>>(codebook, cbb, 524288);
  code_norms<<<2048, 256, 0, stream>>>(codebook, cnorm);

  dim3 gg(8, 64);
  // encoder
  gemm_bias_relu<<<gg, 256, 0, stream>>>(xb, wt0, be1, act, 8192, 1024, 1024);
  ln_kernel<<<8192, 256, 0, stream>>>(act, ge1, bne1, yb, nullptr);
  gemm_bias_relu<<<gg, 256, 0, stream>>>(yb, wt1, be2, act, 8192, 1024, 1024);
  ln_kernel<<<8192, 256, 0, stream>>>(act, ge2, bne2, zb, nullptr);
  // VQ
  vq_dist<<<512, 256, 0, stream>>>(zb, cbb, cnorm, best);
  vq_gather<<<8192, 256, 0, stream>>>(best, codebook, zb, qb, counts, lpart);
  // decoder
  gemm_bias_relu<<<gg, 256, 0, stream>>>(qb, wt2, bd1, act, 8192, 1024, 1024);
  ln_kernel<<<8192, 256, 0, stream>>>(act, gd1, bnd1, yb, nullptr);
  gemm_bias_relu<<<gg, 256, 0, stream>>>(yb, wt3, bd2, act, 8192, 1024, 1024);
  ln_kernel<<<8192, 256, 0, stream>>>(act, gd2, bnd2, nullptr, out);

  finalize<<<1, 256, 0, stream>>>(counts, lpart, out + 8388608);
}